// Round 15
// baseline (131.648 us; speedup 1.0000x reference)
//
#include <hip/hip_runtime.h>

#define BB 1024
#define TT 512
#define KK 64
#define CH 8   // scan steps per chunk

typedef float f32x4 __attribute__((ext_vector_type(4)));

__device__ __forceinline__ float wave_sum(float v) {
#pragma unroll
    for (int off = 1; off < 64; off <<= 1) v += __shfl_xor(v, off);
    return v;
}

__device__ __forceinline__ float wave_max(float v) {
#pragma unroll
    for (int off = 1; off < 64; off <<= 1) v = fmaxf(v, __shfl_xor(v, off));
    return v;
}

#if __has_builtin(__builtin_amdgcn_mov_dpp)
__device__ __forceinline__ float dpp_xor1_f(float x) {
    return __uint_as_float((unsigned)__builtin_amdgcn_mov_dpp(
        (int)__float_as_uint(x), 0xB1, 0xF, 0xF, true));  // quad [1,0,3,2]
}
__device__ __forceinline__ float dpp_xor2_f(float x) {
    return __uint_as_float((unsigned)__builtin_amdgcn_mov_dpp(
        (int)__float_as_uint(x), 0x4E, 0xF, 0xF, true));  // quad [2,3,0,1]
}
#else
__device__ __forceinline__ float dpp_xor1_f(float x) { return __shfl_xor(x, 1); }
__device__ __forceinline__ float dpp_xor2_f(float x) { return __shfl_xor(x, 2); }
#endif

// 4-wave cooperative scan: 256 threads/block, one block per batch element.
// Wave w owns rows 16w..16w+15; within a wave, 4 lanes per row (quad), each
// lane covering a 16-wide k-slice. Per step: read p (f32, double-buffered
// LDS) -> 16 FMA -> quad all-reduce (2 DPP) -> *el *scl -> write own row ->
// lgkmcnt(0) + raw s_barrier (NO vmcnt drain: logits prefetch stays in
// flight across barriers). Rescale is pow-2 exact, derived OFF-chain from
// the read-buffer's p[0] (uniform LDS broadcast read, parallel to dots).
__global__ void __launch_bounds__(256)
crf_fwd(
    const float* __restrict__ logits,
    const float* __restrict__ trans,
    const int* __restrict__ gold,
    const int* __restrict__ seq_len,
    float* __restrict__ ws)
{
    __shared__ __align__(16) float buf[2][KK];   // double-buffered p (f32)
    __shared__ float mxs;
    __shared__ float redA[4], redB[4];

    const int b = blockIdx.x;
    const int tid = threadIdx.x;
    const int u = tid & 63;          // lane in wave
    const int w = tid >> 6;          // wave 0..3
    const int myrow = (w << 4) | (u >> 2);
    const int c = u & 3;             // k-slice index
    const float* lg = logits + (size_t)b * (TT * KK);
    const int* gd = gold + (size_t)b * TT;
    const int L = seq_len[b];

    // ---- Phase A: first & second terms, all 256 threads (latency hides
    // under the scan since af/asec are only consumed at the end) ----
    float af = 0.0f, asec = 0.0f;
#pragma unroll
    for (int q = 0; q < TT / 256; ++q) {
        int t = q * 256 + tid;
        if (t < L) {
            int g0 = gd[t];
            af += lg[t * KK + g0];
            if (t + 1 < L) {
                int g1 = gd[t + 1];
                asec += trans[g0 * KK + g1];
            }
        }
    }

    // ---- E fragment: my row, my 16-wide k-slice, exp()'d, 4 f32x4 regs ----
    f32x4 Ea, Eb, Ec, Ed;
    {
        const float* rp = trans + (size_t)myrow * KK + (c << 4);
        f32x4 v0 = *(const f32x4*)(rp + 0);
        f32x4 v1 = *(const f32x4*)(rp + 4);
        f32x4 v2 = *(const f32x4*)(rp + 8);
        f32x4 v3 = *(const f32x4*)(rp + 12);
        Ea.x = __expf(v0.x); Ea.y = __expf(v0.y); Ea.z = __expf(v0.z); Ea.w = __expf(v0.w);
        Eb.x = __expf(v1.x); Eb.y = __expf(v1.y); Eb.z = __expf(v1.z); Eb.w = __expf(v1.w);
        Ec.x = __expf(v2.x); Ec.y = __expf(v2.y); Ec.z = __expf(v2.z); Ec.w = __expf(v2.w);
        Ed.x = __expf(v3.x); Ed.y = __expf(v3.y); Ed.z = __expf(v3.z); Ed.w = __expf(v3.w);
    }

    // ---- t = 0 init (wave 0 only) ----
    if (w == 0) {
        float a0 = lg[u];
        float mx = wave_max(a0);
        buf[0][u] = __expf(a0 - mx);     // in (0,1]
        if (u == 0) mxs = mx;
    }

    // ---- preload chunk 0 logits for my row (t = 1..8) ----
    f32x4 nl0, nl1;
    nl0.x = lg[1 * KK + myrow]; nl0.y = lg[2 * KK + myrow];
    nl0.z = lg[3 * KK + myrow]; nl0.w = lg[4 * KK + myrow];
    nl1.x = lg[5 * KK + myrow]; nl1.y = lg[6 * KK + myrow];
    nl1.z = lg[7 * KK + myrow]; nl1.w = lg[8 * KK + myrow];

    int Etot = 0;
    int par = 0;   // buffer to READ this step

    // barrier: init writes visible; no vmcnt drain
    asm volatile("s_waitcnt lgkmcnt(0)" ::: "memory");
    __builtin_amdgcn_s_barrier();
    asm volatile("" ::: "memory");

#define STEP(EL) { \
    const float* br_ = &buf[par][0]; \
    float* bw_ = &buf[par ^ 1][0]; \
    /* scl path: uniform broadcast read of p[0], parallel to dot path */ \
    float p0_ = br_[0]; \
    unsigned pb_ = __float_as_uint(p0_); \
    int ee_ = (int)((pb_ >> 23) & 255u) - 127; \
    float scl_ = __uint_as_float((unsigned)((127 - ee_) << 23)); \
    Etot += ee_; \
    /* dot path: my 16-wide slice */ \
    const f32x4* bs_ = (const f32x4*)(br_ + (c << 4)); \
    f32x4 P0_ = bs_[0], P1_ = bs_[1], P2_ = bs_[2], P3_ = bs_[3]; \
    float A0_ = Ea.x * P0_.x, A1_ = Eb.x * P1_.x; \
    float A2_ = Ec.x * P2_.x, A3_ = Ed.x * P3_.x; \
    A0_ = fmaf(Ea.y, P0_.y, A0_); A1_ = fmaf(Eb.y, P1_.y, A1_); \
    A2_ = fmaf(Ec.y, P2_.y, A2_); A3_ = fmaf(Ed.y, P3_.y, A3_); \
    A0_ = fmaf(Ea.z, P0_.z, A0_); A1_ = fmaf(Eb.z, P1_.z, A1_); \
    A2_ = fmaf(Ec.z, P2_.z, A2_); A3_ = fmaf(Ed.z, P3_.z, A3_); \
    A0_ = fmaf(Ea.w, P0_.w, A0_); A1_ = fmaf(Eb.w, P1_.w, A1_); \
    A2_ = fmaf(Ec.w, P2_.w, A2_); A3_ = fmaf(Ed.w, P3_.w, A3_); \
    float s4_ = (A0_ + A1_) + (A2_ + A3_); \
    float sq_ = s4_ + dpp_xor1_f(s4_); \
    sq_ = sq_ + dpp_xor2_f(sq_);            /* full row sum in all 4 lanes */ \
    float pn_ = sq_ * (EL) * scl_; \
    bw_[myrow] = pn_;   /* 4 lanes, same addr, same value: benign */ \
    asm volatile("s_waitcnt lgkmcnt(0)" ::: "memory"); \
    __builtin_amdgcn_s_barrier(); \
    asm volatile("" ::: "memory"); \
    par ^= 1; }

    // ---- main loop: full chunks only ----
    int t0 = 1;
    for (; t0 + CH <= L; t0 += CH) {
        // exp of current chunk's logits (off the critical p-chain)
        f32x4 el0, el1;
        el0.x = __expf(nl0.x); el0.y = __expf(nl0.y);
        el0.z = __expf(nl0.z); el0.w = __expf(nl0.w);
        el1.x = __expf(nl1.x); el1.y = __expf(nl1.y);
        el1.z = __expf(nl1.z); el1.w = __expf(nl1.w);

        // prefetch next chunk (stays in flight across raw barriers)
        {
            int tn = t0 + CH;
            int c0 = tn + 0; c0 = (c0 > TT - 1) ? TT - 1 : c0;
            int c1 = tn + 1; c1 = (c1 > TT - 1) ? TT - 1 : c1;
            int c2 = tn + 2; c2 = (c2 > TT - 1) ? TT - 1 : c2;
            int c3 = tn + 3; c3 = (c3 > TT - 1) ? TT - 1 : c3;
            int c4 = tn + 4; c4 = (c4 > TT - 1) ? TT - 1 : c4;
            int c5 = tn + 5; c5 = (c5 > TT - 1) ? TT - 1 : c5;
            int c6 = tn + 6; c6 = (c6 > TT - 1) ? TT - 1 : c6;
            int c7 = tn + 7; c7 = (c7 > TT - 1) ? TT - 1 : c7;
            nl0.x = lg[c0 * KK + myrow]; nl0.y = lg[c1 * KK + myrow];
            nl0.z = lg[c2 * KK + myrow]; nl0.w = lg[c3 * KK + myrow];
            nl1.x = lg[c4 * KK + myrow]; nl1.y = lg[c5 * KK + myrow];
            nl1.z = lg[c6 * KK + myrow]; nl1.w = lg[c7 * KK + myrow];
        }

        STEP(el0.x) STEP(el0.y) STEP(el0.z) STEP(el0.w)
        STEP(el1.x) STEP(el1.y) STEP(el1.z) STEP(el1.w)
    }

    // ---- remainder: at most CH-1 steps, block-uniform guards ----
    if (t0 < L) {
        f32x4 el0, el1;
        el0.x = __expf(nl0.x); el0.y = __expf(nl0.y);
        el0.z = __expf(nl0.z); el0.w = __expf(nl0.w);
        el1.x = __expf(nl1.x); el1.y = __expf(nl1.y);
        el1.z = __expf(nl1.z); el1.w = __expf(nl1.w);
        if (t0 + 0 < L) { STEP(el0.x) }
        if (t0 + 1 < L) { STEP(el0.y) }
        if (t0 + 2 < L) { STEP(el0.z) }
        if (t0 + 3 < L) { STEP(el0.w) }
        if (t0 + 4 < L) { STEP(el1.x) }
        if (t0 + 5 < L) { STEP(el1.y) }
        if (t0 + 6 < L) { STEP(el1.z) }
    }
#undef STEP

    // ---- block reduction of first/second terms ----
    float afs = wave_sum(af);
    float ass = wave_sum(asec);
    if (u == 0) { redA[w] = afs; redB[w] = ass; }
    __syncthreads();   // end of kernel: vmcnt drain harmless here

    if (w == 0) {
        float pf = buf[par][u];          // final state (written by last STEP)
        float sum = wave_sum(pf);
        if (u == 0) {
            float third = mxs + (float)Etot * 0.6931471805599453f + __logf(sum);
            float first = (redA[0] + redA[1]) + (redA[2] + redA[3]);
            float second = (redB[0] + redB[1]) + (redB[2] + redB[3]);
            ws[b] = (third - first - second) * (1.0f / (float)BB);
        }
    }
}

// Deterministic fixed-order reduction of the 1024 per-b contributions.
__global__ void crf_reduce(const float* __restrict__ ws, float* __restrict__ out) {
    int tid = threadIdx.x;  // 256 threads
    float v = ws[tid] + ws[tid + 256] + ws[tid + 512] + ws[tid + 768];
    v = wave_sum(v);
    __shared__ float sm[4];
    if ((tid & 63) == 0) sm[tid >> 6] = v;
    __syncthreads();
    if (tid == 0) out[0] = (sm[0] + sm[1]) + (sm[2] + sm[3]);
}

extern "C" void kernel_launch(void* const* d_in, const int* in_sizes, int n_in,
                              void* d_out, int out_size, void* d_ws, size_t ws_size,
                              hipStream_t stream) {
    const float* logits = (const float*)d_in[0];
    const float* trans  = (const float*)d_in[1];
    const int*   gold   = (const int*)d_in[2];
    const int*   slen   = (const int*)d_in[3];
    float* out = (float*)d_out;
    float* ws = (float*)d_ws;

    hipLaunchKernelGGL(crf_fwd, dim3(BB), dim3(256), 0, stream,
                       logits, trans, gold, slen, ws);
    hipLaunchKernelGGL(crf_reduce, dim3(1), dim3(256), 0, stream, ws, out);
}

// Round 16
// 86.366 us; speedup vs baseline: 1.5243x; 1.5243x over previous
//
#include <hip/hip_runtime.h>

#define BB 1024
#define TT 512
#define KK 64
#define CH 8   // scan steps per chunk

typedef float f32x4 __attribute__((ext_vector_type(4)));
typedef float f32x2 __attribute__((ext_vector_type(2)));

#define LO2(v4) __builtin_shufflevector((v4), (v4), 0, 1)
#define HI2(v4) __builtin_shufflevector((v4), (v4), 2, 3)

__device__ __forceinline__ float wave_sum(float v) {
#pragma unroll
    for (int off = 1; off < 64; off <<= 1) v += __shfl_xor(v, off);
    return v;
}

__device__ __forceinline__ float wave_max(float v) {
#pragma unroll
    for (int off = 1; off < 64; off <<= 1) v = fmaxf(v, __shfl_xor(v, off));
    return v;
}

#if __has_builtin(__builtin_amdgcn_mov_dpp)
__device__ __forceinline__ float dpp_xor1_f(float x) {
    return __uint_as_float((unsigned)__builtin_amdgcn_mov_dpp(
        (int)__float_as_uint(x), 0xB1, 0xF, 0xF, true));  // quad [1,0,3,2]
}
__device__ __forceinline__ float dpp_xor2_f(float x) {
    return __uint_as_float((unsigned)__builtin_amdgcn_mov_dpp(
        (int)__float_as_uint(x), 0x4E, 0xF, 0xF, true));  // quad [2,3,0,1]
}
#else
__device__ __forceinline__ float dpp_xor1_f(float x) { return __shfl_xor(x, 1); }
__device__ __forceinline__ float dpp_xor2_f(float x) { return __shfl_xor(x, 2); }
#endif

// One wave per batch element; lane j owns state j (r13 k-slice structure —
// r14 MFMA and r15 multi-wave both regressed; single-wave is the regime).
// p in LDS as f32, single buffer (same-wave DS ops are in-order: reads
// precede the write). Per step: 4 ds_read_b128 (my 16-k slice) -> 32
// v_pk_fma_f32 (4 quad rows x 16k) -> PERMUTED-ROW reduce-scatter (rows
// loaded as qr+(c^rr), so Q0=P0+xor1(P1), Q1=P2+xor1(P3), s=Q0+xor2(Q1)
// lands row j in lane j with ZERO cndmasks) -> *el -> store. Renorm is
// pow-2 exact, PER CHUNK, off-chain: exponent of buf[0] folded into el0.
// Worst-case growth e^{8.6*8}+spread < f32 max.
__global__ void __launch_bounds__(64)
__attribute__((amdgpu_waves_per_eu(1, 1)))
crf_fwd(
    const float* __restrict__ logits,
    const float* __restrict__ trans,
    const int* __restrict__ gold,
    const int* __restrict__ seq_len,
    float* __restrict__ ws)
{
    __shared__ __align__(16) float buf[KK];   // p state (f32)
    const int b = blockIdx.x;
    const int j = threadIdx.x & 63;
    const int qr = (j >> 2) << 2;    // quad base row
    const int c = j & 3;             // quad position = k-slice index
    const int sc = c << 4;           // slice col base
    const float* lg = logits + (size_t)b * (TT * KK);
    const int* gd = gold + (size_t)b * TT;
    const int L = seq_len[b];

    // ---- Phase A: lane-parallel first & second terms (off the scan) ----
    float af = 0.0f, asec = 0.0f;
#pragma unroll
    for (int q = 0; q < TT / 64; ++q) {
        int t = q * 64 + j;
        if (t < L) {
            int g0 = gd[t];
            af += lg[t * KK + g0];
            if (t + 1 < L) {
                int g1 = gd[t + 1];
                asec += trans[g0 * KK + g1];
            }
        }
    }

    // ---- E fragment: 4 rows (PERMUTED order qr+(c^rr)) x my 16-k slice,
    //      exp()'d into 32 named f32x2 regs (Erq covers k = sc+2q..2q+1) ----
    f32x2 E00, E01, E02, E03, E04, E05, E06, E07;
    f32x2 E10, E11, E12, E13, E14, E15, E16, E17;
    f32x2 E20, E21, E22, E23, E24, E25, E26, E27;
    f32x2 E30, E31, E32, E33, E34, E35, E36, E37;
#define LDROW(RR, N0, N1, N2, N3, N4, N5, N6, N7) { \
    const float* rp_ = trans + (size_t)(qr + (c ^ (RR))) * KK + sc; \
    f32x4 v0 = *(const f32x4*)(rp_ + 0);  f32x4 v1 = *(const f32x4*)(rp_ + 4); \
    f32x4 v2 = *(const f32x4*)(rp_ + 8);  f32x4 v3 = *(const f32x4*)(rp_ + 12); \
    N0.x = __expf(v0.x); N0.y = __expf(v0.y); N1.x = __expf(v0.z); N1.y = __expf(v0.w); \
    N2.x = __expf(v1.x); N2.y = __expf(v1.y); N3.x = __expf(v1.z); N3.y = __expf(v1.w); \
    N4.x = __expf(v2.x); N4.y = __expf(v2.y); N5.x = __expf(v2.z); N5.y = __expf(v2.w); \
    N6.x = __expf(v3.x); N6.y = __expf(v3.y); N7.x = __expf(v3.z); N7.y = __expf(v3.w); }
    LDROW(0, E00, E01, E02, E03, E04, E05, E06, E07)
    LDROW(1, E10, E11, E12, E13, E14, E15, E16, E17)
    LDROW(2, E20, E21, E22, E23, E24, E25, E26, E27)
    LDROW(3, E30, E31, E32, E33, E34, E35, E36, E37)
#undef LDROW

    // ---- t = 0 init ----
    float a0 = lg[j];
    float mx = wave_max(a0);
    buf[j] = __expf(a0 - mx);       // in (0, 1]
    int Etot = 0;

    // ---- preload chunk 0 (t = 1..8) ----
    f32x4 nl0, nl1;
    nl0.x = lg[1 * KK + j]; nl0.y = lg[2 * KK + j];
    nl0.z = lg[3 * KK + j]; nl0.w = lg[4 * KK + j];
    nl1.x = lg[5 * KK + j]; nl1.y = lg[6 * KK + j];
    nl1.z = lg[7 * KK + j]; nl1.w = lg[8 * KK + j];

#define PK(EH, W, A) A = __builtin_elementwise_fma(EH, (W), A);

    // One step: 4 slice reads -> 32 pk_fma -> permuted-row quad reduce ->
    // *el -> store own row. No in-chain rescale (deferred to chunk top).
#define STEP(EL) { \
    const f32x4* bs_ = (const f32x4*)(buf + sc); \
    f32x4 W0_ = bs_[0], W1_ = bs_[1], W2_ = bs_[2], W3_ = bs_[3]; \
    f32x2 a0_ = {0.f, 0.f}, a1_ = {0.f, 0.f}, a2_ = {0.f, 0.f}, a3_ = {0.f, 0.f}; \
    PK(E00, LO2(W0_), a0_) PK(E10, LO2(W0_), a1_) PK(E20, LO2(W0_), a2_) PK(E30, LO2(W0_), a3_) \
    PK(E01, HI2(W0_), a0_) PK(E11, HI2(W0_), a1_) PK(E21, HI2(W0_), a2_) PK(E31, HI2(W0_), a3_) \
    PK(E02, LO2(W1_), a0_) PK(E12, LO2(W1_), a1_) PK(E22, LO2(W1_), a2_) PK(E32, LO2(W1_), a3_) \
    PK(E03, HI2(W1_), a0_) PK(E13, HI2(W1_), a1_) PK(E23, HI2(W1_), a2_) PK(E33, HI2(W1_), a3_) \
    PK(E04, LO2(W2_), a0_) PK(E14, LO2(W2_), a1_) PK(E24, LO2(W2_), a2_) PK(E34, LO2(W2_), a3_) \
    PK(E05, HI2(W2_), a0_) PK(E15, HI2(W2_), a1_) PK(E25, HI2(W2_), a2_) PK(E35, HI2(W2_), a3_) \
    PK(E06, LO2(W3_), a0_) PK(E16, LO2(W3_), a1_) PK(E26, LO2(W3_), a2_) PK(E36, LO2(W3_), a3_) \
    PK(E07, HI2(W3_), a0_) PK(E17, HI2(W3_), a1_) PK(E27, HI2(W3_), a2_) PK(E37, HI2(W3_), a3_) \
    float P0_ = a0_.x + a0_.y; float P1_ = a1_.x + a1_.y; \
    float P2_ = a2_.x + a2_.y; float P3_ = a3_.x + a3_.y; \
    float Q0_ = P0_ + dpp_xor1_f(P1_); \
    float Q1_ = P2_ + dpp_xor1_f(P3_); \
    float s_ = Q0_ + dpp_xor2_f(Q1_);       /* full row-j sum, lane j */ \
    float pn_ = s_ * (EL); \
    buf[j] = pn_; }

    // ---- main loop: full chunks only (all CH steps strictly < L) ----
    int t0 = 1;
    for (; t0 + CH <= L; t0 += CH) {
        // anti-spill anchors for the 32 E regs
        asm volatile("" : "+v"(E00), "+v"(E01), "+v"(E02), "+v"(E03),
                          "+v"(E04), "+v"(E05), "+v"(E06), "+v"(E07),
                          "+v"(E10), "+v"(E11), "+v"(E12), "+v"(E13),
                          "+v"(E14), "+v"(E15), "+v"(E16), "+v"(E17));
        asm volatile("" : "+v"(E20), "+v"(E21), "+v"(E22), "+v"(E23),
                          "+v"(E24), "+v"(E25), "+v"(E26), "+v"(E27),
                          "+v"(E30), "+v"(E31), "+v"(E32), "+v"(E33),
                          "+v"(E34), "+v"(E35), "+v"(E36), "+v"(E37));

        // exp of current chunk's logits (off the critical p-chain)
        f32x4 el0, el1;
        el0.x = __expf(nl0.x); el0.y = __expf(nl0.y);
        el0.z = __expf(nl0.z); el0.w = __expf(nl0.w);
        el1.x = __expf(nl1.x); el1.y = __expf(nl1.y);
        el1.z = __expf(nl1.z); el1.w = __expf(nl1.w);

        // prefetch next chunk
        {
            int tn = t0 + CH;
            int c0 = tn + 0; c0 = (c0 > TT - 1) ? TT - 1 : c0;
            int c1 = tn + 1; c1 = (c1 > TT - 1) ? TT - 1 : c1;
            int c2 = tn + 2; c2 = (c2 > TT - 1) ? TT - 1 : c2;
            int c3 = tn + 3; c3 = (c3 > TT - 1) ? TT - 1 : c3;
            int c4 = tn + 4; c4 = (c4 > TT - 1) ? TT - 1 : c4;
            int c5 = tn + 5; c5 = (c5 > TT - 1) ? TT - 1 : c5;
            int c6 = tn + 6; c6 = (c6 > TT - 1) ? TT - 1 : c6;
            int c7 = tn + 7; c7 = (c7 > TT - 1) ? TT - 1 : c7;
            nl0.x = lg[c0 * KK + j]; nl0.y = lg[c1 * KK + j];
            nl0.z = lg[c2 * KK + j]; nl0.w = lg[c3 * KK + j];
            nl1.x = lg[c4 * KK + j]; nl1.y = lg[c5 * KK + j];
            nl1.z = lg[c6 * KK + j]; nl1.w = lg[c7 * KK + j];
        }

        // chunk-top renorm (off-chain): fold 2^-exponent(buf[0]) into el0
        {
            float p00 = buf[0];                       // uniform LDS read
            unsigned pb = __float_as_uint(p00);
            int ee = (int)((pb >> 23) & 255u) - 127;
            Etot += ee;
            float scl = __uint_as_float((unsigned)((127 - ee) << 23));
            el0.x *= scl;
        }

        STEP(el0.x) STEP(el0.y) STEP(el0.z) STEP(el0.w)
        STEP(el1.x) STEP(el1.y) STEP(el1.z) STEP(el1.w)
    }

    // ---- remainder: at most CH-1 steps, wave-uniform guards ----
    if (t0 < L) {
        f32x4 el0, el1;
        el0.x = __expf(nl0.x); el0.y = __expf(nl0.y);
        el0.z = __expf(nl0.z); el0.w = __expf(nl0.w);
        el1.x = __expf(nl1.x); el1.y = __expf(nl1.y);
        el1.z = __expf(nl1.z); el1.w = __expf(nl1.w);
        {
            float p00 = buf[0];
            unsigned pb = __float_as_uint(p00);
            int ee = (int)((pb >> 23) & 255u) - 127;
            Etot += ee;
            float scl = __uint_as_float((unsigned)((127 - ee) << 23));
            el0.x *= scl;
        }
        if (t0 + 0 < L) { STEP(el0.x) }
        if (t0 + 1 < L) { STEP(el0.y) }
        if (t0 + 2 < L) { STEP(el0.z) }
        if (t0 + 3 < L) { STEP(el0.w) }
        if (t0 + 4 < L) { STEP(el1.x) }
        if (t0 + 5 < L) { STEP(el1.y) }
        if (t0 + 6 < L) { STEP(el1.z) }
    }
#undef STEP
#undef PK

    float pfin = buf[j];
    float sump = wave_sum(pfin);
    float third_b = mx + (float)Etot * 0.6931471805599453f + __logf(sump);
    float first_b = wave_sum(af);
    float second_b = wave_sum(asec);

    if (j == 0) {
        ws[b] = (third_b - first_b - second_b) * (1.0f / (float)BB);
    }
}

// Deterministic fixed-order reduction of the 1024 per-b contributions.
__global__ void crf_reduce(const float* __restrict__ ws, float* __restrict__ out) {
    int tid = threadIdx.x;  // 256 threads
    float v = ws[tid] + ws[tid + 256] + ws[tid + 512] + ws[tid + 768];
    v = wave_sum(v);
    __shared__ float sm[4];
    if ((tid & 63) == 0) sm[tid >> 6] = v;
    __syncthreads();
    if (tid == 0) out[0] = (sm[0] + sm[1]) + (sm[2] + sm[3]);
}

extern "C" void kernel_launch(void* const* d_in, const int* in_sizes, int n_in,
                              void* d_out, int out_size, void* d_ws, size_t ws_size,
                              hipStream_t stream) {
    const float* logits = (const float*)d_in[0];
    const float* trans  = (const float*)d_in[1];
    const int*   gold   = (const int*)d_in[2];
    const int*   slen   = (const int*)d_in[3];
    float* out = (float*)d_out;
    float* ws = (float*)d_ws;

    hipLaunchKernelGGL(crf_fwd, dim3(BB), dim3(64), 0, stream,
                       logits, trans, gold, slen, ws);
    hipLaunchKernelGGL(crf_reduce, dim3(1), dim3(256), 0, stream, ws, out);
}